// Round 5
// baseline (27519.278 us; speedup 1.0000x reference)
//
#include <hip/hip_runtime.h>
#include <stdint.h>

// ============================================================================
// RNNModel: emb-lookup -> BiGRU(E=128->H=256) -> BiGRU(512->256) -> MLP+BN ->
//           dense(61) -> softmax + mask.   B=64, S=2048, H=256, V=61.
//
// Round 5: latency-focused scan rewrite.
//  - single barrier/step (ping-pong hbuf) via "s_waitcnt lgkmcnt(0); s_barrier"
//    inline asm: NO vmcnt drain -> h stores + gate loads float across barrier.
//  - packed gates [row][j][(r,z,n,pad)] -> one 8B load per (batch,j) for both
//    the layer-0 token table (LDS) and layer-1 gi chunks (global).
//  - bn_stats: block-local reduce, 2 atomics/col/block (was 262k atomics).
// ws 256 MiB: fixed 3.64 + h1 128 + y1pre 32 + gi(packed) 64 + hc 16 = 243.5 MiB
// ============================================================================

#define SS 2048
#define NEGV -1000000000.0f
#define HPAD 264   // hbuf row stride (ushort): b128 reads land 2-way (free)

__device__ __forceinline__ float bf2f(unsigned short u) {
    union { unsigned int i; float f; } v; v.i = ((unsigned int)u) << 16; return v.f;
}
__device__ __forceinline__ unsigned short f2bf(float f) {
    union { float f; unsigned int i; } v; v.f = f;
    unsigned int i = v.i;
    return (unsigned short)((i + 0x7fffu + ((i >> 16) & 1u)) >> 16);
}
__device__ __forceinline__ float2 bfpair(unsigned int u) {
    union { unsigned int i; float f; } a, b;
    a.i = u << 16; b.i = u & 0xffff0000u;
    float2 r; r.x = a.f; r.y = b.f; return r;
}
// workgroup barrier WITHOUT vmcnt drain (LDS ordering only)
__device__ __forceinline__ void sync_lds() {
    asm volatile("s_waitcnt lgkmcnt(0)\ns_barrier" ::: "memory");
}

typedef __attribute__((ext_vector_type(8))) short bf16x8_t;
typedef __attribute__((ext_vector_type(4))) float f32x4_t;

// ---------------------------------------------------------------------------
__global__ void zero_stats_kernel(float* st) {
    st[blockIdx.x*256 + threadIdx.x] = 0.0f;   // 4 x 256 = 1024 floats
}

__global__ void init_y1_kernel(unsigned short* y1, const float* b1) {
    size_t total = 131072ull*128;
    for (size_t i = blockIdx.x*(size_t)blockDim.x + threadIdx.x; i < total;
         i += (size_t)gridDim.x*blockDim.x)
        y1[i] = f2bf(b1[i & 127]);
}

// ---------------------------------------------------------------------------
// Prep. T0p: packed layer-0 gate tables [dir][21 tok][256 j][4:(r,z,n,0)] bf16.
// whhbf: [dl][768][256] bf16.  w123: w1f|w1b|w2|w3 bf16.
// ---------------------------------------------------------------------------
__global__ void prep_kernel(
    const float* emb,
    const float* wih0f, const float* bih0f, const float* bhh0f,
    const float* wih0b, const float* bih0b, const float* bhh0b,
    const float* whh0f, const float* whh0b, const float* whh1f, const float* whh1b,
    const float* wih1f, const float* wih1b,
    const float* bih1f, const float* bhh1f, const float* bih1b, const float* bhh1b,
    const float* w1, const float* w2, const float* w3,
    unsigned short* T0p, unsigned short* whhbf, unsigned short* wih1bf,
    unsigned short* w123, float* bias1, float* bhn)
{
    const int NA = 2*21*1024;     // packed T0 entries
    const int NB = 4*768*256;     // whhbf
    const int NC = 2*768*512;     // wih1
    const int ND = 131072;        // w1f|w1b|w2|w3
    const int NE = 2*768 + 4*256; // bias1 + bhn
    int total = NA + NB + NC + ND + NE;
    for (int idx = blockIdx.x*blockDim.x + threadIdx.x; idx < total;
         idx += gridDim.x*blockDim.x) {
        int i = idx;
        if (i < NA) {
            int d = i / 21504; int rem = i % 21504;
            int tok = rem / 1024; int jj = rem % 1024;
            int j = jj >> 2, g = jj & 3;
            if (g == 3) { T0p[i] = 0; continue; }
            int n = g*256 + j;
            const float* wih = d ? wih0b : wih0f;
            const float* bih = d ? bih0b : bih0f;
            const float* bhh = d ? bhh0b : bhh0f;
            float s = bih[n] + (g < 2 ? bhh[n] : 0.0f);
            const float* er = emb + tok*128;
            const float* wr = wih + n*128;
            for (int e = 0; e < 128; e++) s += er[e]*wr[e];
            T0p[i] = f2bf(s);
            continue;
        }
        i -= NA;
        if (i < NB) {
            int dl = i / 196608; int rem = i % 196608;
            const float* whh = dl==0 ? whh0f : dl==1 ? whh0b : dl==2 ? whh1f : whh1b;
            whhbf[i] = f2bf(whh[rem]);
            continue;
        }
        i -= NB;
        if (i < NC) {
            int d = i / (768*512); int rem = i % (768*512);
            const float* w = d ? wih1b : wih1f;
            wih1bf[i] = f2bf(w[rem]);
            continue;
        }
        i -= NC;
        if (i < ND) {
            float v;
            if (i < 32768)       { int n = i >> 8, k = i & 255; v = w1[n*512 + k]; }
            else if (i < 65536)  { int r = i - 32768; int n = r >> 8, k = r & 255; v = w1[n*512 + 256 + k]; }
            else if (i < 98304)  v = w2[i - 65536];
            else                 v = w3[i - 98304];
            w123[i] = f2bf(v);
            continue;
        }
        i -= ND;
        if (i < 2*768) {
            int d = i / 768; int j = i % 768;
            const float* bih = d ? bih1b : bih1f;
            const float* bhh = d ? bhh1b : bhh1f;
            bias1[i] = bih[j] + (j < 512 ? bhh[j] : 0.0f);
            continue;
        }
        i -= 2*768;
        {
            int dl = i / 256; int j = i % 256;
            const float* bhh = dl==0 ? bhh0f : dl==1 ? bhh0b : dl==2 ? bhh1f : bhh1b;
            bhn[i] = bhh[512 + j];
        }
    }
}

// ---------------------------------------------------------------------------
// Weight-stationary MFMA GRU scan, single-barrier ping-pong version.
// Block = 512 thr (8 waves), grid = 8 (dir*4 + bg).  Wave wv owns gate tiles
// {2wv, 2wv+1} (+16, +32 for z, n) -> j1 = {2wv*16+col, (2wv+1)*16+col}.
// gi (layer1) and T0s (layer0) are PACKED: row stride 1024 ushort, entry
// [j*4] = (r,z,n,pad) -> one uint2 load per (batch, j).
// ---------------------------------------------------------------------------
__global__ __launch_bounds__(512, 2) void scan_mfma_kernel(
    const int* x, const int* lens, const unsigned short* T0p,
    const unsigned short* gi_f, const unsigned short* gi_b,
    const unsigned short* whh, const float* bhn, float* hstate,
    unsigned short* h1out, unsigned short* hfc, unsigned short* hbc,
    int layer, int t0, int tc, int first)
{
    __shared__ __align__(16) unsigned short T0s[21*1024];
    __shared__ __align__(16) unsigned short hbuf[2*16*HPAD];
    const int dir = blockIdx.x >> 2;
    const int bg  = blockIdx.x & 3;
    const int tid = threadIdx.x;
    const int wv = tid >> 6, lane = tid & 63;
    const int col = lane & 15, quad = lane >> 4;
    const int dl = layer*2 + dir;
    const int b0 = bg*16;

    if (layer == 0) {
        const unsigned short* Ts = T0p + dir*21504;
        for (int i = tid; i < 21504; i += 512) T0s[i] = Ts[i];
    }

    // weight fragments: VGPR/AGPR-resident for the whole kernel
    bf16x8_t wf[6][8];
    {
        const unsigned short* Wd = whh + (size_t)dl*768*256;
        #pragma unroll
        for (int g = 0; g < 3; g++)
            #pragma unroll
            for (int jt = 0; jt < 2; jt++) {
                int n = g*256 + (2*wv + jt)*16 + col;
                const unsigned short* base = Wd + (size_t)n*256 + quad*8;
                #pragma unroll
                for (int kt = 0; kt < 8; kt++)
                    wf[g*2+jt][kt] = *(const bf16x8_t*)(base + kt*32);
            }
    }

    int j1[2]; j1[0] = (2*wv)*16 + col; j1[1] = (2*wv+1)*16 + col;
    float bhnv[2];
    bhnv[0] = bhn[dl*256 + j1[0]];
    bhnv[1] = bhn[dl*256 + j1[1]];

    int len_q[4];
    float hr[4][2];
    #pragma unroll
    for (int q = 0; q < 4; q++) {
        int bl = quad*4 + q;
        len_q[q] = lens[b0 + bl];
        #pragma unroll
        for (int jt = 0; jt < 2; jt++)
            hr[q][jt] = first ? 0.0f
                      : hstate[(size_t)(dir*64 + b0 + bl)*256 + j1[jt]];
    }
    for (int i = tid; i < 16*256; i += 512) {
        int bb = i >> 8, k = i & 255;
        float hv = first ? 0.0f : hstate[(size_t)(dir*64 + b0 + bb)*256 + k];
        hbuf[bb*HPAD + k] = f2bf(hv);
    }
    __syncthreads();

    const int maxlen = lens[b0];   // batches sorted descending
    int tend = t0 + tc; if (tend > maxlen) tend = maxlen; if (tend < t0) tend = t0;
    const unsigned short* gi = dir ? gi_b : gi_f;
    unsigned short* hco = dir ? hbc : hfc;

    int cur = 0;
    for (int t = t0; t < tend; t++) {
        const unsigned short* hb_r = hbuf + cur*(16*HPAD);
        unsigned short* hb_w = hbuf + (cur ^ 1)*(16*HPAD);

        // ---- gate loads (packed, 8B per (batch, j)) — long latency, issue 1st
        uint2 gpk[4][2];
        if (layer == 0) {
            #pragma unroll
            for (int q = 0; q < 4; q++) {
                int len = len_q[q];
                int p = dir ? (len - 1 - t) : t;
                if (p < 0) p = 0;
                int tok = x[(size_t)(b0 + quad*4 + q)*SS + p];
                #pragma unroll
                for (int jt = 0; jt < 2; jt++)
                    gpk[q][jt] = *(const uint2*)(T0s + tok*1024 + j1[jt]*4);
            }
        } else {
            #pragma unroll
            for (int q = 0; q < 4; q++) {
                const unsigned short* gp = gi + ((size_t)(t - t0)*64 + b0 + quad*4 + q)*1024;
                #pragma unroll
                for (int jt = 0; jt < 2; jt++)
                    gpk[q][jt] = *(const uint2*)(gp + j1[jt]*4);
            }
        }

        // ---- MFMA: G[16 batch, 768 gate] = H @ W_hh^T
        f32x4_t acc[6];
        #pragma unroll
        for (int f = 0; f < 6; f++) acc[f] = (f32x4_t){0.f,0.f,0.f,0.f};
        #pragma unroll
        for (int kt = 0; kt < 8; kt++) {
            bf16x8_t a = *(const bf16x8_t*)(hb_r + col*HPAD + kt*32 + quad*8);
            #pragma unroll
            for (int f = 0; f < 6; f++)
                acc[f] = __builtin_amdgcn_mfma_f32_16x16x32_bf16(a, wf[f][kt], acc[f], 0, 0, 0);
        }

        // ---- epilogue
        #pragma unroll
        for (int q = 0; q < 4; q++) {
            int bl = quad*4 + q;
            bool valid = t < len_q[q];
            #pragma unroll
            for (int jt = 0; jt < 2; jt++) {
                float gr = bf2f((unsigned short)(gpk[q][jt].x));
                float gz = bf2f((unsigned short)(gpk[q][jt].x >> 16));
                float gn = bf2f((unsigned short)(gpk[q][jt].y));
                float rr = 1.0f/(1.0f + __expf(-(acc[jt][q]   + gr)));
                float zz = 1.0f/(1.0f + __expf(-(acc[2+jt][q] + gz)));
                float ar = gn + rr*(acc[4+jt][q] + bhnv[jt]);
                float nn = 2.0f/(1.0f + __expf(-2.0f*ar)) - 1.0f;
                float hn = (1.0f - zz)*nn + zz*hr[q][jt];
                if (valid) hr[q][jt] = hn;
                unsigned short hb = f2bf(hr[q][jt]);
                hb_w[bl*HPAD + j1[jt]] = hb;        // always: carry frozen h too
                if (layer == 0) {
                    if (valid) {
                        int tout = dir ? (len_q[q] - 1 - t) : t;
                        h1out[((size_t)(b0+bl)*SS + tout)*512 + dir*256 + j1[jt]] = hb;
                    }
                } else {
                    hco[((size_t)(t - t0)*64 + b0 + bl)*256 + j1[jt]] = valid ? hb : (unsigned short)0;
                }
            }
        }
        sync_lds();        // LDS-only barrier: stores/loads float across
        cur ^= 1;
    }

    // zero-fill hco tail where whole block is past maxlen
    if (layer == 1) {
        for (int t = tend; t < t0 + tc; t++) {
            #pragma unroll
            for (int q = 0; q < 4; q++) {
                int bl = quad*4 + q;
                size_t o = ((size_t)(t - t0)*64 + b0 + bl)*256;
                hco[o + j1[0]] = 0;
                hco[o + j1[1]] = 0;
            }
        }
    }
    #pragma unroll
    for (int q = 0; q < 4; q++) {
        int bl = quad*4 + q;
        hstate[(size_t)(dir*64 + b0 + bl)*256 + j1[0]] = hr[q][0];
        hstate[(size_t)(dir*64 + b0 + bl)*256 + j1[1]] = hr[q][1];
    }
}

// ---------------------------------------------------------------------------
// bf16 MFMA GEMM.  amode: 0 r | 1 b*S+(t0+t) | 2 b*S+clamp(len-1-(t0+t),0)
// cmode: 0 plain | 1 b*S+(t0+t) | 2 b*S+(len-1-(t0+t)) skip s<0 | 3 packed-gi
// ---------------------------------------------------------------------------
__global__ __launch_bounds__(256) void gemm_kernel(
    const unsigned short* A, const unsigned short* W, const float* bias,
    unsigned short* C, int N, int K, int amode, int cmode, int accum,
    const int* lens, int t0)
{
    int lane = threadIdx.x & 63;
    int wv = threadIdx.x >> 6;
    int n0 = blockIdx.x*64 + wv*16;
    int m0 = blockIdx.y*16;
    int rA = m0 + (lane & 15);
    int arow;
    if (amode == 0) arow = rA;
    else {
        int bb = rA & 63; int t = t0 + (rA >> 6);
        if (amode == 1) arow = bb*SS + t;
        else { int tt = lens[bb] - 1 - t; if (tt < 0) tt = 0; arow = bb*SS + tt; }
    }
    const unsigned short* Ap = A + (size_t)arow*K + (lane >> 4)*8;
    const unsigned short* Wp = W + (size_t)(n0 + (lane & 15))*K + (lane >> 4)*8;
    f32x4_t acc = {0.f, 0.f, 0.f, 0.f};
    for (int k0 = 0; k0 < K; k0 += 32) {
        bf16x8_t a = *(const bf16x8_t*)(Ap + k0);
        bf16x8_t w = *(const bf16x8_t*)(Wp + k0);
        acc = __builtin_amdgcn_mfma_f32_16x16x32_bf16(a, w, acc, 0, 0, 0);
    }
    int n = n0 + (lane & 15);
    float bv = bias ? bias[n] : 0.0f;
    int mbase = m0 + (lane >> 4)*4;
    for (int q = 0; q < 4; q++) {
        int r = mbase + q;
        float v = acc[q] + bv;
        size_t idx; bool valid = true;
        if (cmode == 0) idx = (size_t)r*N + n;
        else if (cmode == 3) idx = (size_t)r*1024 + (size_t)(n & 255)*4 + (n >> 8);
        else {
            int bb = r & 63; int t = t0 + (r >> 6);
            if (cmode == 1) idx = ((size_t)bb*SS + t)*N + n;
            else {
                int s = lens[bb] - 1 - t;
                if (s < 0) { valid = false; idx = 0; }
                else idx = ((size_t)bb*SS + s)*N + n;
            }
        }
        if (valid) {
            if (accum) v += bf2f(C[idx]);
            C[idx] = f2bf(v);
        }
    }
}

// ---------------------------------------------------------------------------
// BatchNorm stats: block-local accumulate + LDS reduce, 2 atomics/col/block.
// grid = 32 blocks x 256 thr; M = 131072 rows fixed; N in {128, 256}.
// ---------------------------------------------------------------------------
__global__ __launch_bounds__(256) void bn_stats_kernel(const unsigned short* y,
                                                       int N, float* st)
{
    __shared__ float ls[256], l2[256];
    int tid = threadIdx.x;
    int c = tid & (N - 1);
    int s = tid / N;
    int slabs = 256 / N;
    size_t r0 = (size_t)blockIdx.x * 4096;
    float sum = 0.f, sq = 0.f;
    for (int r = s; r < 4096; r += slabs) {
        float v = bf2f(y[(r0 + r)*(size_t)N + c]);
        sum += v; sq += v*v;
    }
    ls[tid] = sum; l2[tid] = sq;
    __syncthreads();
    if (tid < N) {
        for (int k = 1; k < slabs; k++) { sum += ls[tid + k*N]; sq += l2[tid + k*N]; }
        atomicAdd(&st[c], sum);
        atomicAdd(&st[N + c], sq);
    }
}

__global__ void bn_apply_kernel(unsigned short* y, const float* st,
                                const float* g, const float* be, int N)
{
    const int M = 131072;
    size_t total = (size_t)M*N;
    float invM = 1.0f / M;
    for (size_t i = blockIdx.x*(size_t)blockDim.x + threadIdx.x; i < total;
         i += (size_t)gridDim.x*blockDim.x) {
        int c = (int)(i % N);
        float mean = st[c]*invM;
        float var = fmaxf(st[N + c]*invM - mean*mean, 0.0f);
        float v = bf2f(y[i]);
        v = g[c]*(v - mean)*rsqrtf(var + 1e-5f) + be[c];
        y[i] = f2bf(v >= 0.f ? v : 0.01f*v);
    }
}

// ---------------------------------------------------------------------------
// Final dense(61) + softmax + mask. One wave per (b,t) row.
// ---------------------------------------------------------------------------
__constant__ int c_lo[21] = {0,0,4,10,12,14,16,18,20,24,26,29,35,36,37,39,43,49,53,57,58};
__constant__ int c_hi[21] = {0,4,10,12,14,16,18,20,24,26,29,35,36,37,39,43,49,53,57,58,60};

__global__ __launch_bounds__(256) void out_kernel(
    const unsigned short* o3, const float* w4, const float* b4,
    const int* x, const int* lens, float* out)
{
    __shared__ __align__(16) float w4t[128*64];
    __shared__ float b4s[64];
    for (int i = threadIdx.x; i < 61*128; i += 256) {
        int v = i / 128, k = i % 128;
        w4t[k*64 + v] = w4[i];
    }
    if (threadIdx.x < 64) b4s[threadIdx.x] = threadIdx.x < 61 ? b4[threadIdx.x] : 0.f;
    __syncthreads();
    int wv = threadIdx.x >> 6;
    int lane = threadIdx.x & 63;
    int row = blockIdx.x*4 + wv;
    int b = row >> 11;
    int t = row & 2047;
    const unsigned int* o3r = (const unsigned int*)(o3 + (size_t)row*128);
    float dot;
    if (lane < 61) {
        dot = 0.f;
        for (int k2 = 0; k2 < 64; k2++) {
            float2 p = bfpair(o3r[k2]);
            dot += p.x * w4t[(2*k2)*64 + lane] + p.y * w4t[(2*k2 + 1)*64 + lane];
        }
        dot += b4s[lane];
    } else dot = -1e30f;
    float mx = dot;
    for (int off = 32; off >= 1; off >>= 1) mx = fmaxf(mx, __shfl_xor(mx, off, 64));
    float e = (lane < 61) ? __expf(dot - mx) : 0.f;
    float sm = e;
    for (int off = 32; off >= 1; off >>= 1) sm += __shfl_xor(sm, off, 64);
    float p = e / sm;
    if (lane < 61) {
        int tok = x[row];
        int len = lens[b];
        float maskv = NEGV;
        if (t < len && tok > 0 && lane >= c_lo[tok] && lane < c_hi[tok]) maskv = 0.f;
        out[(size_t)row*61 + lane] = p + maskv;
    }
}

// ---------------------------------------------------------------------------
__global__ void mask_only_kernel(const int* x, const int* lens, float* out)
{
    int row = blockIdx.x*blockDim.x + threadIdx.x;
    if (row >= 64*SS) return;
    int b = row >> 11, t = row & 2047;
    int tok = x[row], len = lens[b];
    float* o = out + (size_t)row*61;
    int lo = c_lo[tok], hi = c_hi[tok];
    for (int v = 0; v < 61; v++) {
        float m = NEGV;
        if (t < len && tok > 0 && v >= lo && v < hi) m = 0.f;
        o[v] = m;
    }
}

// ---------------------------------------------------------------------------
extern "C" void kernel_launch(void* const* d_in, const int* in_sizes, int n_in,
                              void* d_out, int out_size, void* d_ws, size_t ws_size,
                              hipStream_t stream)
{
    (void)in_sizes; (void)n_in; (void)out_size;
    const int*   x     = (const int*)  d_in[0];
    const int*   lens  = (const int*)  d_in[1];
    const float* emb   = (const float*)d_in[2];
    const float* wih0f = (const float*)d_in[3];
    const float* whh0f = (const float*)d_in[4];
    const float* bih0f = (const float*)d_in[5];
    const float* bhh0f = (const float*)d_in[6];
    const float* wih0b = (const float*)d_in[7];
    const float* whh0b = (const float*)d_in[8];
    const float* bih0b = (const float*)d_in[9];
    const float* bhh0b = (const float*)d_in[10];
    const float* wih1f = (const float*)d_in[11];
    const float* whh1f = (const float*)d_in[12];
    const float* bih1f = (const float*)d_in[13];
    const float* bhh1f = (const float*)d_in[14];
    const float* wih1b = (const float*)d_in[15];
    const float* whh1b = (const float*)d_in[16];
    const float* bih1b = (const float*)d_in[17];
    const float* bhh1b = (const float*)d_in[18];
    const float* w1  = (const float*)d_in[19];
    const float* b1  = (const float*)d_in[20];
    const float* g1  = (const float*)d_in[21];
    const float* be1 = (const float*)d_in[22];
    const float* w2  = (const float*)d_in[23];
    const float* b2  = (const float*)d_in[24];
    const float* g2  = (const float*)d_in[25];
    const float* be2 = (const float*)d_in[26];
    const float* w3  = (const float*)d_in[27];
    const float* b3  = (const float*)d_in[28];
    const float* g3  = (const float*)d_in[29];
    const float* be3 = (const float*)d_in[30];
    const float* w4  = (const float*)d_in[31];
    const float* b4  = (const float*)d_in[32];

    // ---- fixed region (offsets 256-aligned) ----
    char* ws = (char*)d_ws;
    unsigned short* T0p    = (unsigned short*)(ws + 0);        //    86,016
    unsigned short* whhbf  = (unsigned short*)(ws + 86016);    // 1,572,864
    unsigned short* wih1bf = (unsigned short*)(ws + 1658880);  // 1,572,864
    unsigned short* w123   = (unsigned short*)(ws + 3231744);  //   262,144
    float*          bias1  = (float*)(ws + 3493888);           //     6,144
    float*          bhn    = (float*)(ws + 3500032);           //     4,096
    float*          stats  = (float*)(ws + 3504128);           //     4,096
    float*          hstate = (float*)(ws + 3508224);           //   131,072
    const size_t OFF_H1  = 3639296;
    const size_t H1SZ    = 134217728ull;          // 64*2048*512 bf16
    const size_t Y1SZ    = 33554432ull;           // 131072*128 bf16
    const size_t OFF_Y1  = OFF_H1 + H1SZ;
    const size_t OFF_GI  = OFF_Y1 + Y1SZ;         // 171,411,456

    // per-TC chunk: packed gi 2 x TC*65536 ushort + hc 2 x TC*16384 ushort
    int TC = 0;
    for (int tc = 256; tc >= 32; tc >>= 1) {
        if (ws_size >= OFF_GI + (size_t)tc*327680ull) { TC = tc; break; }
    }
    if (TC == 0) { mask_only_kernel<<<512, 256, 0, stream>>>(x, lens, (float*)d_out); return; }

    unsigned short* h1    = (unsigned short*)(ws + OFF_H1);
    unsigned short* y1pre = (unsigned short*)(ws + OFF_Y1);
    unsigned short* gi_f  = (unsigned short*)(ws + OFF_GI);
    unsigned short* gi_b  = gi_f + (size_t)TC*65536;
    unsigned short* hfc   = gi_b + (size_t)TC*65536;
    unsigned short* hbc   = hfc  + (size_t)TC*16384;
    unsigned short* y2    = h1;                          // h1 dead after chunks
    unsigned short* y3    = (unsigned short*)(ws + OFF_H1 + 67108864ull);

    zero_stats_kernel<<<4, 256, 0, stream>>>(stats);
    prep_kernel<<<1024, 256, 0, stream>>>(emb, wih0f, bih0f, bhh0f, wih0b, bih0b, bhh0b,
        whh0f, whh0b, whh1f, whh1b, wih1f, wih1b, bih1f, bhh1f, bih1b, bhh1b,
        w1, w2, w3, T0p, whhbf, wih1bf, w123, bias1, bhn);
    init_y1_kernel<<<2048, 256, 0, stream>>>(y1pre, b1);

    // layer 0 scan -> h1
    scan_mfma_kernel<<<8, 512, 0, stream>>>(x, lens, T0p, nullptr, nullptr,
        whhbf, bhn, hstate, h1, nullptr, nullptr, 0, 0, SS, 1);

    // layer 1 chunks
    int NCH = SS / TC;
    for (int c = 0; c < NCH; c++) {
        int t0 = c*TC;
        gemm_kernel<<<dim3(12, TC*4), 256, 0, stream>>>(h1, wih1bf, bias1,
            gi_f, 768, 512, 1, 3, 0, lens, t0);
        gemm_kernel<<<dim3(12, TC*4), 256, 0, stream>>>(h1, wih1bf + 768*512, bias1 + 768,
            gi_b, 768, 512, 2, 3, 0, lens, t0);
        scan_mfma_kernel<<<8, 512, 0, stream>>>(x, lens, T0p, gi_f, gi_b,
            whhbf, bhn, hstate, nullptr, hfc, hbc, 1, t0, TC, c == 0);
        gemm_kernel<<<dim3(2, TC*4), 256, 0, stream>>>(hfc, w123, nullptr,
            y1pre, 128, 256, 0, 1, 1, lens, t0);
        gemm_kernel<<<dim3(2, TC*4), 256, 0, stream>>>(hbc, w123 + 32768, nullptr,
            y1pre, 128, 256, 0, 2, 1, lens, t0);
    }

    // MLP + BN chain
    bn_stats_kernel<<<32, 256, 0, stream>>>(y1pre, 128, stats);
    bn_apply_kernel<<<2048, 256, 0, stream>>>(y1pre, stats, g1, be1, 128);

    gemm_kernel<<<dim3(4, 8192), 256, 0, stream>>>(y1pre, w123 + 65536, b2,
        y2, 256, 128, 0, 0, 0, nullptr, 0);
    bn_stats_kernel<<<32, 256, 0, stream>>>(y2, 256, stats + 256);
    bn_apply_kernel<<<4096, 256, 0, stream>>>(y2, stats + 256, g2, be2, 256);

    gemm_kernel<<<dim3(2, 8192), 256, 0, stream>>>(y2, w123 + 98304, b3,
        y3, 128, 256, 0, 0, 0, nullptr, 0);
    bn_stats_kernel<<<32, 256, 0, stream>>>(y3, 128, stats + 768);
    bn_apply_kernel<<<2048, 256, 0, stream>>>(y3, stats + 768, g3, be3, 128);

    // final dense(61) + softmax + mask
    out_kernel<<<32768, 256, 0, stream>>>(y3, w4, b4, x, lens, (float*)d_out);
}

// Round 6
// 25517.415 us; speedup vs baseline: 1.0785x; 1.0785x over previous
//
#include <hip/hip_runtime.h>
#include <stdint.h>

// ============================================================================
// RNNModel: emb-lookup -> BiGRU(E=128->H=256) -> BiGRU(512->256) -> MLP+BN ->
//           dense(61) -> softmax + mask.   B=64, S=2048, H=256, V=61.
//
// Round 6: scan critical path stripped of memory waits.
//  - tokens staged to LDS per 256-step chunk (layer 0); gates prefetched one
//    step ahead into regs (LDS for layer 0, global gi for layer 1, issued
//    BEFORE the h stores so vmcnt FIFO wait doesn't include store acks).
//  - lgkm-only barriers (2/step): stores + prefetches float across.
//  - h1 time-major [t*64+b][512]: coalesced writes, sequential gi-gemm reads.
//  - bn stats/apply vectorized; per-col scale/shift precomputed.
// ============================================================================

#define SS 2048
#define NEGV -1000000000.0f
#define HPAD 264   // hbuf row stride (ushort): 528 B, 16B-aligned rows
#define TPAD 272   // tokLDS row stride (ushort)
#define CHK 256    // token staging chunk (steps)

__device__ __forceinline__ float bf2f(unsigned short u) {
    union { unsigned int i; float f; } v; v.i = ((unsigned int)u) << 16; return v.f;
}
__device__ __forceinline__ unsigned short f2bf(float f) {
    union { float f; unsigned int i; } v; v.f = f;
    unsigned int i = v.i;
    return (unsigned short)((i + 0x7fffu + ((i >> 16) & 1u)) >> 16);
}
__device__ __forceinline__ float2 bfpair(unsigned int u) {
    union { unsigned int i; float f; } a, b;
    a.i = u << 16; b.i = u & 0xffff0000u;
    float2 r; r.x = a.f; r.y = b.f; return r;
}
// workgroup barrier WITHOUT vmcnt drain (LDS ordering only)
__device__ __forceinline__ void sync_lds() {
    asm volatile("s_waitcnt lgkmcnt(0)\ns_barrier" ::: "memory");
}

typedef __attribute__((ext_vector_type(8))) short bf16x8_t;
typedef __attribute__((ext_vector_type(4))) float f32x4_t;

// ---------------------------------------------------------------------------
__global__ void zero_stats_kernel(float* st) {
    st[blockIdx.x*256 + threadIdx.x] = 0.0f;   // 16 x 256 = 4096 floats
}

__global__ void init_y1_kernel(unsigned short* y1, const float* b1) {
    // y1pre[131072][128] = b1 broadcast, vectorized 8-wide
    size_t totalv = 131072ull*16;    // uint4 count
    for (size_t iv = blockIdx.x*(size_t)blockDim.x + threadIdx.x; iv < totalv;
         iv += (size_t)gridDim.x*blockDim.x) {
        int cg = ((int)(iv & 15)) << 3;
        uint4 o;
        o.x = (unsigned)f2bf(b1[cg])   | ((unsigned)f2bf(b1[cg+1]) << 16);
        o.y = (unsigned)f2bf(b1[cg+2]) | ((unsigned)f2bf(b1[cg+3]) << 16);
        o.z = (unsigned)f2bf(b1[cg+4]) | ((unsigned)f2bf(b1[cg+5]) << 16);
        o.w = (unsigned)f2bf(b1[cg+6]) | ((unsigned)f2bf(b1[cg+7]) << 16);
        ((uint4*)y1)[iv] = o;
    }
}

// ---------------------------------------------------------------------------
// Prep. T0p: packed layer-0 gate tables [dir][21 tok][256 j][4:(r,z,n,0)] bf16.
// whhbf: [dl][768][256] bf16.  w123: w1f|w1b|w2|w3 bf16.
// ---------------------------------------------------------------------------
__global__ void prep_kernel(
    const float* emb,
    const float* wih0f, const float* bih0f, const float* bhh0f,
    const float* wih0b, const float* bih0b, const float* bhh0b,
    const float* whh0f, const float* whh0b, const float* whh1f, const float* whh1b,
    const float* wih1f, const float* wih1b,
    const float* bih1f, const float* bhh1f, const float* bih1b, const float* bhh1b,
    const float* w1, const float* w2, const float* w3,
    unsigned short* T0p, unsigned short* whhbf, unsigned short* wih1bf,
    unsigned short* w123, float* bias1, float* bhn)
{
    const int NA = 2*21*1024;     // packed T0 entries
    const int NB = 4*768*256;     // whhbf
    const int NC = 2*768*512;     // wih1
    const int ND = 131072;        // w1f|w1b|w2|w3
    const int NE = 2*768 + 4*256; // bias1 + bhn
    int total = NA + NB + NC + ND + NE;
    for (int idx = blockIdx.x*blockDim.x + threadIdx.x; idx < total;
         idx += gridDim.x*blockDim.x) {
        int i = idx;
        if (i < NA) {
            int d = i / 21504; int rem = i % 21504;
            int tok = rem / 1024; int jj = rem % 1024;
            int j = jj >> 2, g = jj & 3;
            if (g == 3) { T0p[i] = 0; continue; }
            int n = g*256 + j;
            const float* wih = d ? wih0b : wih0f;
            const float* bih = d ? bih0b : bih0f;
            const float* bhh = d ? bhh0b : bhh0f;
            float s = bih[n] + (g < 2 ? bhh[n] : 0.0f);
            const float* er = emb + tok*128;
            const float* wr = wih + n*128;
            for (int e = 0; e < 128; e++) s += er[e]*wr[e];
            T0p[i] = f2bf(s);
            continue;
        }
        i -= NA;
        if (i < NB) {
            int dl = i / 196608; int rem = i % 196608;
            const float* whh = dl==0 ? whh0f : dl==1 ? whh0b : dl==2 ? whh1f : whh1b;
            whhbf[i] = f2bf(whh[rem]);
            continue;
        }
        i -= NB;
        if (i < NC) {
            int d = i / (768*512); int rem = i % (768*512);
            const float* w = d ? wih1b : wih1f;
            wih1bf[i] = f2bf(w[rem]);
            continue;
        }
        i -= NC;
        if (i < ND) {
            float v;
            if (i < 32768)       { int n = i >> 8, k = i & 255; v = w1[n*512 + k]; }
            else if (i < 65536)  { int r = i - 32768; int n = r >> 8, k = r & 255; v = w1[n*512 + 256 + k]; }
            else if (i < 98304)  v = w2[i - 65536];
            else                 v = w3[i - 98304];
            w123[i] = f2bf(v);
            continue;
        }
        i -= ND;
        if (i < 2*768) {
            int d = i / 768; int j = i % 768;
            const float* bih = d ? bih1b : bih1f;
            const float* bhh = d ? bhh1b : bhh1f;
            bias1[i] = bih[j] + (j < 512 ? bhh[j] : 0.0f);
            continue;
        }
        i -= 2*768;
        {
            int dl = i / 256; int j = i % 256;
            const float* bhh = dl==0 ? bhh0f : dl==1 ? bhh0b : dl==2 ? bhh1f : bhh1b;
            bhn[i] = bhh[512 + j];
        }
    }
}

// ---------------------------------------------------------------------------
// Weight-stationary MFMA GRU scan.
// Block = 512 thr (8 waves), grid = 8 (dir*4 + bg). Wave wv owns gate tiles
// j1 = {2wv*16+col, (2wv+1)*16+col} for r,z,n. Single hbuf, 2 lgkm barriers.
// Gates for step t+1 prefetched during step t (regs); layer-0 tokens staged
// to LDS per CHK steps. h1out is time-major [t*64+b][512].
// ---------------------------------------------------------------------------
__global__ __launch_bounds__(512, 2) void scan_mfma_kernel(
    const int* x, const int* lens, const unsigned short* T0p,
    const unsigned short* gi_f, const unsigned short* gi_b,
    const unsigned short* whh, const float* bhn, float* hstate,
    unsigned short* h1out, unsigned short* hfc, unsigned short* hbc,
    int layer, int t0, int tc, int first)
{
    __shared__ __align__(16) unsigned short T0s[21*1024];
    __shared__ __align__(16) unsigned short tokLDS[16*TPAD];
    __shared__ __align__(16) unsigned short hbuf[16*HPAD];
    const int dir = blockIdx.x >> 2;
    const int bg  = blockIdx.x & 3;
    const int tid = threadIdx.x;
    const int wv = tid >> 6, lane = tid & 63;
    const int col = lane & 15, quad = lane >> 4;
    const int dl = layer*2 + dir;
    const int b0 = bg*16;

    if (layer == 0) {
        const unsigned short* Ts = T0p + dir*21504;
        for (int i = tid; i < 21504; i += 512) T0s[i] = Ts[i];
    }

    // weight fragments: VGPR/AGPR-resident for the whole kernel
    bf16x8_t wf[6][8];
    {
        const unsigned short* Wd = whh + (size_t)dl*768*256;
        #pragma unroll
        for (int g = 0; g < 3; g++)
            #pragma unroll
            for (int jt = 0; jt < 2; jt++) {
                int n = g*256 + (2*wv + jt)*16 + col;
                const unsigned short* base = Wd + (size_t)n*256 + quad*8;
                #pragma unroll
                for (int kt = 0; kt < 8; kt++)
                    wf[g*2+jt][kt] = *(const bf16x8_t*)(base + kt*32);
            }
    }

    int j1[2]; j1[0] = (2*wv)*16 + col; j1[1] = (2*wv+1)*16 + col;
    float bhnv[2];
    bhnv[0] = bhn[dl*256 + j1[0]];
    bhnv[1] = bhn[dl*256 + j1[1]];

    int len_q[4];
    float hr[4][2];
    #pragma unroll
    for (int q = 0; q < 4; q++) {
        int bl = quad*4 + q;
        len_q[q] = lens[b0 + bl];
        #pragma unroll
        for (int jt = 0; jt < 2; jt++)
            hr[q][jt] = first ? 0.0f
                      : hstate[(size_t)(dir*64 + b0 + bl)*256 + j1[jt]];
    }
    for (int i = tid; i < 16*256; i += 512) {
        int bb = i >> 8, k = i & 255;
        float hv = first ? 0.0f : hstate[(size_t)(dir*64 + b0 + bb)*256 + k];
        hbuf[bb*HPAD + k] = f2bf(hv);
    }
    __syncthreads();

    int tend = t0 + tc;
    { int ml = lens[b0]; if (tend > ml) tend = ml; if (tend < t0) tend = t0; }
    const unsigned short* gi = dir ? gi_b : gi_f;
    unsigned short* hco = dir ? hbc : hfc;

    uint2 gc[4][2];
    int prim = 1;

    for (int tb = t0; tb < tend; tb += CHK) {
        int te = tb + CHK; if (te > tend) te = tend;
        if (layer == 0) {
            sync_lds();   // prior tokLDS reads done
            // stage tokens for scan-steps [tb, tb+CHK+1] (clamped)
            for (int i = tid; i < 16*(CHK+2); i += 512) {
                int bb = i / (CHK+2), tl = i % (CHK+2);
                int len = lens[b0 + bb];
                int p = dir ? (len - 1 - (tb + tl)) : (tb + tl);
                if (p < 0) p = 0;
                if (p > len - 1) p = len - 1;
                tokLDS[bb*TPAD + tl] = (unsigned short)x[(size_t)(b0 + bb)*SS + p];
            }
        }
        sync_lds();       // staging visible (harmless extra barrier for layer 1)
        if (prim) {       // gates for the very first step
            prim = 0;
            if (layer == 0) {
                #pragma unroll
                for (int q = 0; q < 4; q++) {
                    int tk = tokLDS[(quad*4 + q)*TPAD + 0];
                    gc[q][0] = *(const uint2*)(T0s + tk*1024 + j1[0]*4);
                    gc[q][1] = *(const uint2*)(T0s + tk*1024 + j1[1]*4);
                }
            } else {
                #pragma unroll
                for (int q = 0; q < 4; q++) {
                    const unsigned short* gp = gi + ((size_t)(b0 + quad*4 + q))*1024;
                    gc[q][0] = *(const uint2*)(gp + j1[0]*4);
                    gc[q][1] = *(const uint2*)(gp + j1[1]*4);
                }
            }
        }

        #pragma unroll 1
        for (int t = tb; t < te; t++) {
            // ---- MFMA: G[16 batch, 768 gate] = H @ W_hh^T
            f32x4_t acc[6];
            #pragma unroll
            for (int f = 0; f < 6; f++) acc[f] = (f32x4_t){0.f,0.f,0.f,0.f};
            #pragma unroll
            for (int kt = 0; kt < 8; kt++) {
                bf16x8_t a = *(const bf16x8_t*)(hbuf + col*HPAD + kt*32 + quad*8);
                #pragma unroll
                for (int f = 0; f < 6; f++)
                    acc[f] = __builtin_amdgcn_mfma_f32_16x16x32_bf16(a, wf[f][kt], acc[f], 0, 0, 0);
            }

            // ---- unpack current gates to floats (frees gc for prefetch)
            float gv[4][2][3];
            #pragma unroll
            for (int q = 0; q < 4; q++)
                #pragma unroll
                for (int jt = 0; jt < 2; jt++) {
                    gv[q][jt][0] = bf2f((unsigned short)(gc[q][jt].x));
                    gv[q][jt][1] = bf2f((unsigned short)(gc[q][jt].x >> 16));
                    gv[q][jt][2] = bf2f((unsigned short)(gc[q][jt].y));
                }

            // ---- prefetch gates for t+1 (issued BEFORE stores: vmcnt FIFO)
            if (layer == 0) {
                int tl = t + 1 - tb;   // <= CHK, staged
                #pragma unroll
                for (int q = 0; q < 4; q++) {
                    int tk = tokLDS[(quad*4 + q)*TPAD + tl];
                    gc[q][0] = *(const uint2*)(T0s + tk*1024 + j1[0]*4);
                    gc[q][1] = *(const uint2*)(T0s + tk*1024 + j1[1]*4);
                }
            } else {
                int rl = t + 1 - t0; if (rl > tc - 1) rl = tc - 1;
                #pragma unroll
                for (int q = 0; q < 4; q++) {
                    const unsigned short* gp = gi + ((size_t)rl*64 + b0 + quad*4 + q)*1024;
                    gc[q][0] = *(const uint2*)(gp + j1[0]*4);
                    gc[q][1] = *(const uint2*)(gp + j1[1]*4);
                }
            }

            // ---- gate nonlinearity + h update + output stores
            #pragma unroll
            for (int q = 0; q < 4; q++) {
                int bl = quad*4 + q;
                bool valid = t < len_q[q];
                #pragma unroll
                for (int jt = 0; jt < 2; jt++) {
                    float rr = 1.0f/(1.0f + __expf(-(acc[jt][q]   + gv[q][jt][0])));
                    float zz = 1.0f/(1.0f + __expf(-(acc[2+jt][q] + gv[q][jt][1])));
                    float ar = gv[q][jt][2] + rr*(acc[4+jt][q] + bhnv[jt]);
                    float nn = 2.0f/(1.0f + __expf(-2.0f*ar)) - 1.0f;
                    float hn = (1.0f - zz)*nn + zz*hr[q][jt];
                    if (valid) hr[q][jt] = hn;
                    unsigned short hb = f2bf(hr[q][jt]);
                    if (layer == 0) {
                        if (valid) {
                            int tout = dir ? (len_q[q] - 1 - t) : t;
                            h1out[((size_t)tout*64 + b0 + bl)*512 + dir*256 + j1[jt]] = hb;
                        }
                    } else {
                        hco[((size_t)(t - t0)*64 + b0 + bl)*256 + j1[jt]] =
                            valid ? hb : (unsigned short)0;
                    }
                }
            }

            sync_lds();      // all hbuf reads of step t done
            #pragma unroll
            for (int q = 0; q < 4; q++) {
                int bl = quad*4 + q;
                if (t < len_q[q]) {
                    hbuf[bl*HPAD + j1[0]] = f2bf(hr[q][0]);
                    hbuf[bl*HPAD + j1[1]] = f2bf(hr[q][1]);
                }
            }
            sync_lds();      // writes visible for step t+1
        }
    }

    // zero-fill hco tail where whole block is past maxlen
    if (layer == 1) {
        for (int t = tend; t < t0 + tc; t++) {
            #pragma unroll
            for (int q = 0; q < 4; q++) {
                int bl = quad*4 + q;
                size_t o = ((size_t)(t - t0)*64 + b0 + bl)*256;
                hco[o + j1[0]] = 0;
                hco[o + j1[1]] = 0;
            }
        }
    }
    #pragma unroll
    for (int q = 0; q < 4; q++) {
        int bl = quad*4 + q;
        hstate[(size_t)(dir*64 + b0 + bl)*256 + j1[0]] = hr[q][0];
        hstate[(size_t)(dir*64 + b0 + bl)*256 + j1[1]] = hr[q][1];
    }
}

// ---------------------------------------------------------------------------
// bf16 MFMA GEMM.  amode: 0 arow=r | 2 time-major reversed:
//   r=(t<<6)|b -> arow = clamp(len[b]-1-(t0+t),0)*64 + b
// cmode: 0 plain | 1 (b*S+t0+t)*N+n | 2 (b*S+len-1-t0-t)*N+n skip s<0
//        | 3 packed-gi idx = r*1024 + (n&255)*4 + (n>>8)
// ---------------------------------------------------------------------------
__global__ __launch_bounds__(256) void gemm_kernel(
    const unsigned short* A, const unsigned short* W, const float* bias,
    unsigned short* C, int N, int K, int amode, int cmode, int accum,
    const int* lens, int t0)
{
    int lane = threadIdx.x & 63;
    int wv = threadIdx.x >> 6;
    int n0 = blockIdx.x*64 + wv*16;
    int m0 = blockIdx.y*16;
    int rA = m0 + (lane & 15);
    int arow;
    if (amode == 0) arow = rA;
    else {
        int bb = rA & 63; int t = t0 + (rA >> 6);
        int tt = lens[bb] - 1 - t; if (tt < 0) tt = 0;
        arow = tt*64 + bb;
    }
    const unsigned short* Ap = A + (size_t)arow*K + (lane >> 4)*8;
    const unsigned short* Wp = W + (size_t)(n0 + (lane & 15))*K + (lane >> 4)*8;
    f32x4_t acc = {0.f, 0.f, 0.f, 0.f};
    for (int k0 = 0; k0 < K; k0 += 32) {
        bf16x8_t a = *(const bf16x8_t*)(Ap + k0);
        bf16x8_t w = *(const bf16x8_t*)(Wp + k0);
        acc = __builtin_amdgcn_mfma_f32_16x16x32_bf16(a, w, acc, 0, 0, 0);
    }
    int n = n0 + (lane & 15);
    float bv = bias ? bias[n] : 0.0f;
    int mbase = m0 + (lane >> 4)*4;
    for (int q = 0; q < 4; q++) {
        int r = mbase + q;
        float v = acc[q] + bv;
        size_t idx; bool valid = true;
        if (cmode == 0) idx = (size_t)r*N + n;
        else if (cmode == 3) idx = (size_t)r*1024 + (size_t)(n & 255)*4 + (n >> 8);
        else {
            int bb = r & 63; int t = t0 + (r >> 6);
            if (cmode == 1) idx = ((size_t)bb*SS + t)*N + n;
            else {
                int s = lens[bb] - 1 - t;
                if (s < 0) { valid = false; idx = 0; }
                else idx = ((size_t)bb*SS + s)*N + n;
            }
        }
        if (valid) {
            if (accum) v += bf2f(C[idx]);
            C[idx] = f2bf(v);
        }
    }
}

// ---------------------------------------------------------------------------
// BatchNorm: stats (vectorized, LDS reduce, 2 atomics/col/block), finalize
// (per-col scale/shift), apply (+leaky, vectorized, in-place).
// st layout per stage: [0,N) sum | [N,2N) sumsq | [2N,3N) a | [3N,4N) b
// ---------------------------------------------------------------------------
__global__ __launch_bounds__(256) void bn_stats_kernel(const unsigned short* y,
                                                       int N, float* st)
{
    __shared__ float ls[2048];
    int tid = threadIdx.x;
    int G = N >> 3;            // col-groups of 8 (16 or 32)
    int S = 256 / G;           // row slabs
    int g = tid % G, s = tid / G;
    size_t r0 = (size_t)blockIdx.x * 512;
    float sum[8], sq[8];
    #pragma unroll
    for (int k = 0; k < 8; k++) { sum[k] = 0.f; sq[k] = 0.f; }
    for (int r = s; r < 512; r += S) {
        uint4 u = *(const uint4*)(y + (r0 + r)*(size_t)N + g*8);
        unsigned int w[4] = {u.x, u.y, u.z, u.w};
        #pragma unroll
        for (int p = 0; p < 4; p++) {
            float2 v = bfpair(w[p]);
            sum[2*p] += v.x;   sq[2*p] += v.x*v.x;
            sum[2*p+1] += v.y; sq[2*p+1] += v.y*v.y;
        }
    }
    #pragma unroll
    for (int k = 0; k < 8; k++) ls[tid*8 + k] = sum[k];
    __syncthreads();
    if (tid < N) {
        int g0 = tid >> 3, k0 = tid & 7;
        float acc = 0.f;
        for (int ss = 0; ss < S; ss++) acc += ls[(ss*G + g0)*8 + k0];
        atomicAdd(&st[tid], acc);
    }
    __syncthreads();
    #pragma unroll
    for (int k = 0; k < 8; k++) ls[tid*8 + k] = sq[k];
    __syncthreads();
    if (tid < N) {
        int g0 = tid >> 3, k0 = tid & 7;
        float acc = 0.f;
        for (int ss = 0; ss < S; ss++) acc += ls[(ss*G + g0)*8 + k0];
        atomicAdd(&st[N + tid], acc);
    }
}

__global__ void bn_fin_kernel(float* st, const float* g, const float* be, int N)
{
    int c = threadIdx.x;
    if (c < N) {
        const float invM = 1.0f/131072.0f;
        float mean = st[c]*invM;
        float var = fmaxf(st[N + c]*invM - mean*mean, 0.0f);
        float a = g[c]*rsqrtf(var + 1e-5f);
        st[2*N + c] = a;
        st[3*N + c] = be[c] - a*mean;
    }
}

__global__ void bn_apply_kernel(unsigned short* y, const float* st, int N)
{
    const float* sa = st + 2*N;
    const float* sb = st + 3*N;
    int ng8 = N >> 3;
    size_t totalv = (size_t)131072 * ng8;
    for (size_t iv = blockIdx.x*(size_t)blockDim.x + threadIdx.x; iv < totalv;
         iv += (size_t)gridDim.x*blockDim.x) {
        int cg = ((int)(iv % ng8)) << 3;
        uint4 u = ((const uint4*)y)[iv];
        unsigned int w[4] = {u.x, u.y, u.z, u.w};
        unsigned int o[4];
        #pragma unroll
        for (int p = 0; p < 4; p++) {
            float2 v = bfpair(w[p]);
            int c0 = cg + 2*p;
            float v0 = sa[c0]*v.x + sb[c0];
            float v1 = sa[c0+1]*v.y + sb[c0+1];
            v0 = v0 >= 0.f ? v0 : 0.01f*v0;
            v1 = v1 >= 0.f ? v1 : 0.01f*v1;
            o[p] = (unsigned)f2bf(v0) | ((unsigned)f2bf(v1) << 16);
        }
        uint4 ou; ou.x = o[0]; ou.y = o[1]; ou.z = o[2]; ou.w = o[3];
        ((uint4*)y)[iv] = ou;
    }
}

// ---------------------------------------------------------------------------
// Final dense(61) + softmax + mask. One wave per (b,t) row.
// ---------------------------------------------------------------------------
__constant__ int c_lo[21] = {0,0,4,10,12,14,16,18,20,24,26,29,35,36,37,39,43,49,53,57,58};
__constant__ int c_hi[21] = {0,4,10,12,14,16,18,20,24,26,29,35,36,37,39,43,49,53,57,58,60};

__global__ __launch_bounds__(256) void out_kernel(
    const unsigned short* o3, const float* w4, const float* b4,
    const int* x, const int* lens, float* out)
{
    __shared__ __align__(16) float w4t[128*64];
    __shared__ float b4s[64];
    for (int i = threadIdx.x; i < 61*128; i += 256) {
        int v = i / 128, k = i % 128;
        w4t[k*64 + v] = w4[i];
    }
    if (threadIdx.x < 64) b4s[threadIdx.x] = threadIdx.x < 61 ? b4[threadIdx.x] : 0.f;
    __syncthreads();
    int wv = threadIdx.x >> 6;
    int lane = threadIdx.x & 63;
    int row = blockIdx.x*4 + wv;
    int b = row >> 11;
    int t = row & 2047;
    const unsigned int* o3r = (const unsigned int*)(o3 + (size_t)row*128);
    float dot;
    if (lane < 61) {
        dot = 0.f;
        for (int k2 = 0; k2 < 64; k2++) {
            float2 p = bfpair(o3r[k2]);
            dot += p.x * w4t[(2*k2)*64 + lane] + p.y * w4t[(2*k2 + 1)*64 + lane];
        }
        dot += b4s[lane];
    } else dot = -1e30f;
    float mx = dot;
    for (int off = 32; off >= 1; off >>= 1) mx = fmaxf(mx, __shfl_xor(mx, off, 64));
    float e = (lane < 61) ? __expf(dot - mx) : 0.f;
    float sm = e;
    for (int off = 32; off >= 1; off >>= 1) sm += __shfl_xor(sm, off, 64);
    float p = e / sm;
    if (lane < 61) {
        int tok = x[row];
        int len = lens[b];
        float maskv = NEGV;
        if (t < len && tok > 0 && lane >= c_lo[tok] && lane < c_hi[tok]) maskv = 0.f;
        out[(size_t)row*61 + lane] = p + maskv;
    }
}

// ---------------------------------------------------------------------------
__global__ void mask_only_kernel(const int* x, const int* lens, float* out)
{
    int row = blockIdx.x*blockDim.x + threadIdx.x;
    if (row >= 64*SS) return;
    int b = row >> 11, t = row & 2047;
    int tok = x[row], len = lens[b];
    float* o = out + (size_t)row*61;
    int lo = c_lo[tok], hi = c_hi[tok];
    for (int v = 0; v < 61; v++) {
        float m = NEGV;
        if (t < len && tok > 0 && v >= lo && v < hi) m = 0.f;
        o[v] = m;
    }
}

// ---------------------------------------------------------------------------
extern "C" void kernel_launch(void* const* d_in, const int* in_sizes, int n_in,
                              void* d_out, int out_size, void* d_ws, size_t ws_size,
                              hipStream_t stream)
{
    (void)in_sizes; (void)n_in; (void)out_size;
    const int*   x     = (const int*)  d_in[0];
    const int*   lens  = (const int*)  d_in[1];
    const float* emb   = (const float*)d_in[2];
    const float* wih0f = (const float*)d_in[3];
    const float* whh0f = (const float*)d_in[4];
    const float* bih0f = (const float*)d_in[5];
    const float* bhh0f = (const float*)d_in[6];
    const float* wih0b = (const float*)d_in[7];
    const float* whh0b = (const float*)d_in[8];
    const float* bih0b = (const float*)d_in[9];
    const float* bhh0b = (const float*)d_in[10];
    const float* wih1f = (const float*)d_in[11];
    const float* whh1f = (const float*)d_in[12];
    const float* bih1f = (const float*)d_in[13];
    const float* bhh1f = (const float*)d_in[14];
    const float* wih1b = (const float*)d_in[15];
    const float* whh1b = (const float*)d_in[16];
    const float* bih1b = (const float*)d_in[17];
    const float* bhh1b = (const float*)d_in[18];
    const float* w1  = (const float*)d_in[19];
    const float* b1  = (const float*)d_in[20];
    const float* g1  = (const float*)d_in[21];
    const float* be1 = (const float*)d_in[22];
    const float* w2  = (const float*)d_in[23];
    const float* b2  = (const float*)d_in[24];
    const float* g2  = (const float*)d_in[25];
    const float* be2 = (const float*)d_in[26];
    const float* w3  = (const float*)d_in[27];
    const float* b3  = (const float*)d_in[28];
    const float* g3  = (const float*)d_in[29];
    const float* be3 = (const float*)d_in[30];
    const float* w4  = (const float*)d_in[31];
    const float* b4  = (const float*)d_in[32];

    // ---- fixed region (offsets 256-aligned) ----
    char* ws = (char*)d_ws;
    unsigned short* T0p    = (unsigned short*)(ws + 0);        //    86,016
    unsigned short* whhbf  = (unsigned short*)(ws + 86016);    // 1,572,864
    unsigned short* wih1bf = (unsigned short*)(ws + 1658880);  // 1,572,864
    unsigned short* w123   = (unsigned short*)(ws + 3231744);  //   262,144
    float*          bias1  = (float*)(ws + 3493888);           //     6,144
    float*          bhn    = (float*)(ws + 3500032);           //     4,096
    float*          stats  = (float*)(ws + 3504128);           //    16,384
    float*          hstate = (float*)(ws + 3520512);           //   131,072
    const size_t OFF_H1  = 3651584;
    const size_t H1SZ    = 134217728ull;          // 2048*64*512 bf16 (time-major)
    const size_t Y1SZ    = 33554432ull;           // 131072*128 bf16
    const size_t OFF_Y1  = OFF_H1 + H1SZ;
    const size_t OFF_GI  = OFF_Y1 + Y1SZ;         // 171,423,744

    // per-TC chunk: packed gi 2 x TC*65536 ushort + hc 2 x TC*16384 ushort
    int TC = 0;
    for (int tc = 256; tc >= 32; tc >>= 1) {
        if (ws_size >= OFF_GI + (size_t)tc*327680ull) { TC = tc; break; }
    }
    if (TC == 0) { mask_only_kernel<<<512, 256, 0, stream>>>(x, lens, (float*)d_out); return; }

    unsigned short* h1    = (unsigned short*)(ws + OFF_H1);
    unsigned short* y1pre = (unsigned short*)(ws + OFF_Y1);
    unsigned short* gi_f  = (unsigned short*)(ws + OFF_GI);
    unsigned short* gi_b  = gi_f + (size_t)TC*65536;
    unsigned short* hfc   = gi_b + (size_t)TC*65536;
    unsigned short* hbc   = hfc  + (size_t)TC*16384;
    unsigned short* y2    = h1;                          // h1 dead after chunks
    unsigned short* y3    = (unsigned short*)(ws + OFF_H1 + 67108864ull);

    zero_stats_kernel<<<16, 256, 0, stream>>>(stats);
    prep_kernel<<<1024, 256, 0, stream>>>(emb, wih0f, bih0f, bhh0f, wih0b, bih0b, bhh0b,
        whh0f, whh0b, whh1f, whh1b, wih1f, wih1b, bih1f, bhh1f, bih1b, bhh1b,
        w1, w2, w3, T0p, whhbf, wih1bf, w123, bias1, bhn);
    init_y1_kernel<<<1024, 256, 0, stream>>>(y1pre, b1);

    // layer 0 scan -> h1 (time-major)
    scan_mfma_kernel<<<8, 512, 0, stream>>>(x, lens, T0p, nullptr, nullptr,
        whhbf, bhn, hstate, h1, nullptr, nullptr, 0, 0, SS, 1);

    // layer 1 chunks
    int NCH = SS / TC;
    for (int c = 0; c < NCH; c++) {
        int t0 = c*TC;
        gemm_kernel<<<dim3(12, TC*4), 256, 0, stream>>>(h1 + (size_t)t0*32768, wih1bf,
            bias1, gi_f, 768, 512, 0, 3, 0, lens, t0);
        gemm_kernel<<<dim3(12, TC*4), 256, 0, stream>>>(h1, wih1bf + 768*512,
            bias1 + 768, gi_b, 768, 512, 2, 3, 0, lens, t0);
        scan_mfma_kernel<<<8, 512, 0, stream>>>(x, lens, T0p, gi_f, gi_b,
            whhbf, bhn, hstate, nullptr, hfc, hbc, 1, t0, TC, c == 0);
        gemm_kernel<<<dim3(2, TC*4), 256, 0, stream>>>(hfc, w123, nullptr,
            y1pre, 128, 256, 0, 1, 1, lens, t0);
        gemm_kernel<<<dim3(2, TC*4), 256, 0, stream>>>(hbc, w123 + 32768, nullptr,
            y1pre, 128, 256, 0, 2, 1, lens, t0);
    }

    // MLP + BN chain
    bn_stats_kernel<<<256, 256, 0, stream>>>(y1pre, 128, stats);
    bn_fin_kernel<<<1, 256, 0, stream>>>(stats, g1, be1, 128);
    bn_apply_kernel<<<1024, 256, 0, stream>>>(y1pre, stats, 128);

    gemm_kernel<<<dim3(4, 8192), 256, 0, stream>>>(y1pre, w123 + 65536, b2,
        y2, 256, 128, 0, 0, 0, nullptr, 0);
    bn_stats_kernel<<<256, 256, 0, stream>>>(y2, 256, stats + 1024);
    bn_fin_kernel<<<1, 256, 0, stream>>>(stats + 1024, g2, be2, 256);
    bn_apply_kernel<<<1024, 256, 0, stream>>>(y2, stats + 1024, 256);

    gemm_kernel<<<dim3(2, 8192), 256, 0, stream>>>(y2, w123 + 98304, b3,
        y3, 128, 256, 0, 0, 0, nullptr, 0);
    bn_stats_kernel<<<256, 256, 0, stream>>>(y3, 128, stats + 2048);
    bn_fin_kernel<<<1, 256, 0, stream>>>(stats + 2048, g3, be3, 128);
    bn_apply_kernel<<<1024, 256, 0, stream>>>(y3, stats + 2048, 128);

    // final dense(61) + softmax + mask
    out_kernel<<<32768, 256, 0, stream>>>(y3, w4, b4, x, lens, (float*)d_out);
}